// Round 3
// baseline (326.652 us; speedup 1.0000x reference)
//
#include <hip/hip_runtime.h>
#include <math.h>

// HyperbolicGRUCell: B=32768, I=H=512, c=0.01 (sqrt_c = 0.1)
// R8: LDS-FREE gemm. Diagnosis (R6/R7 counters): two pipeline restructures
//   both neutral at ~122us, MfmaUtil ~37%. Per half-stage slot = ~2290cy vs
//   930cy MFMA floor; LDS pipe carries DMA-writes (40KB) + frag reads (80KB)
//   per CU per half-stage -> LDS total BW is the structural ceiling.
//   Fix: load A and W fragments DIRECTLY global->VGPR (10 dwordx4/wave per
//   half-stage, same bytes, no LDS transit, no barriers). 2-way intra-block
//   reuse served by L1/L2. X/H alternation = natural 2-set ping-pong;
//   compiler inserts minimal counted vmcnt.
//   Grid: 1D, cb fastest (bid&7) -> per-XCD-resident W panels (round-robin
//   XCD assignment), A row-panels HBM-fetched once.
//   1) prep_kernel : log-map + bf16 cvt -> ws chunks [kc][row]
//   2) wcvt_kernel : W fp32 -> bf16 in staging order [cb][kb][g][q][n]
//   3) gru_gemm    : BM=128 BN=64, 4 waves 2m x 2n, no LDS, no barriers
//   4) expmap      : in-place exp-map on out

typedef __attribute__((ext_vector_type(8))) short bf16x8;
typedef __attribute__((ext_vector_type(8))) unsigned short u16x8;
typedef __attribute__((ext_vector_type(4))) float f32x4;

__device__ __forceinline__ unsigned short f2bf(float f) {
    unsigned int u = __float_as_uint(f);
    u += 0x7FFFu + ((u >> 16) & 1u);
    return (unsigned short)(u >> 16);
}

__device__ __forceinline__ u16x8 cvt8(float4 v0, float4 v1, float s) {
    u16x8 r;
    r[0] = f2bf(v0.x * s); r[1] = f2bf(v0.y * s); r[2] = f2bf(v0.z * s); r[3] = f2bf(v0.w * s);
    r[4] = f2bf(v1.x * s); r[5] = f2bf(v1.y * s); r[6] = f2bf(v1.z * s); r[7] = f2bf(v1.w * s);
    return r;
}

__device__ __forceinline__ float sigm(float v) { return 1.f / (1.f + __expf(-v)); }
__device__ __forceinline__ float tanh_fast(float v) { return 1.f - 2.f / (__expf(2.f * v) + 1.f); }

// ---------------------------------------------------------------------------
// 1) prep: 32 rows/block, 8 lanes/row; coalesced reads, LDS transpose so the
//    [kc][row] chunk writes are 512B-contiguous runs.
// ---------------------------------------------------------------------------
__global__ void prep_kernel(const float* __restrict__ x, const float* __restrict__ h,
                            u16x8* __restrict__ xt, u16x8* __restrict__ ht,
                            float* __restrict__ mh, int B) {
    __shared__ u16x8 lbuf[32 * 65];
    int t = threadIdx.x;
    int row = t >> 3, c8 = t & 7;
    int r0 = blockIdx.x * 32;
    bool is_h = (blockIdx.y == 1);
    const float* src = is_h ? h : x;
    const float4* p4 = (const float4*)src + (size_t)(r0 + row) * 128;

    float4 v[8][2];
    float s = 0.f;
    #pragma unroll
    for (int i = 0; i < 8; ++i) {
        int j = i * 16 + c8 * 2;
        v[i][0] = p4[j]; v[i][1] = p4[j + 1];
        s += v[i][0].x * v[i][0].x + v[i][0].y * v[i][0].y + v[i][0].z * v[i][0].z + v[i][0].w * v[i][0].w
           + v[i][1].x * v[i][1].x + v[i][1].y * v[i][1].y + v[i][1].z * v[i][1].z + v[i][1].w * v[i][1].w;
    }
    #pragma unroll
    for (int off = 4; off; off >>= 1) s += __shfl_xor(s, off);
    float norm = fmaxf(sqrtf(s), 1e-15f);
    float a = fminf(0.1f * norm, 1.f - 1e-5f);
    float m = 0.5f * (log1pf(a) - log1pf(-a)) / (0.1f * norm);

    #pragma unroll
    for (int i = 0; i < 8; ++i)
        lbuf[row * 65 + i * 8 + c8] = cvt8(v[i][0], v[i][1], m);
    if (is_h && c8 == 0) mh[r0 + row] = m;
    __syncthreads();

    u16x8* dst = is_h ? ht : xt;
    #pragma unroll
    for (int it = 0; it < 8; ++it) {
        int u = it * 256 + t;
        int rr = u & 31, kc = u >> 5;
        dst[(size_t)kc * B + r0 + rr] = lbuf[rr * 65 + kc];
    }
}

// ---------------------------------------------------------------------------
// 2) weight cvt+permute: chunk C = (cb*16+kb)*1536 + g*256 + q*64 + n
// ---------------------------------------------------------------------------
__global__ void wcvt_kernel(const float* __restrict__ Wih, const float* __restrict__ Whh,
                            u16x8* __restrict__ wst) {
    int C = blockIdx.x * 256 + threadIdx.x;
    int n  = C & 63;
    int q  = (C >> 6) & 3;
    int t2 = C >> 8;
    int g  = t2 % 6;
    int t3 = t2 / 6;
    int kb = t3 & 15;
    int cb = t3 >> 4;
    const float* src = (g < 3) ? Wih : Whh;
    int grow = (g % 3) * 512 + cb * 64 + n;
    int col0 = kb * 32 + q * 8;
    const float4* p = (const float4*)(src + (size_t)grow * 512 + col0);
    wst[C] = cvt8(p[0], p[1], 1.f);
}

// ---------------------------------------------------------------------------
// 3) fused dual-GEMM + GRU, LDS-free. Per wave per half-stage:
//    4 A-frag + 6 W-frag global_load_dwordx4 into VGPRs, 24 MFMA.
//    Schedule per kb: MFMA_X(kb) | loadX(kb+1) | MFMA_H(kb) | loadH(kb+1).
//    Compiler's minimal vmcnt waits implement the counted pipeline.
// ---------------------------------------------------------------------------
__launch_bounds__(256, 2)
__global__ void gru_gemm_kernel(const u16x8* __restrict__ xt, const u16x8* __restrict__ ht,
                                const u16x8* __restrict__ wst,
                                const float* __restrict__ h, const float* __restrict__ mh,
                                const float* __restrict__ bih, const float* __restrict__ bhh,
                                float* __restrict__ out, int B) {
    int t = threadIdx.x;
    int w = t >> 6, lane = t & 63;
    int quad = lane >> 4, lr = lane & 15;
    int wm = w >> 1, wn = w & 1;
    int bid = blockIdx.x;
    int cb = bid & 7;                    // cb fastest -> XCD-resident W panel
    int r0 = (bid >> 3) * 128;

    // A frag source: chunk (kb*4+quad)*B + r0 + wm*64 + rh*16 + lr
    const u16x8* pax = xt + (size_t)quad * B + r0 + wm * 64 + lr;
    const u16x8* pah = ht + (size_t)quad * B + r0 + wm * 64 + lr;
    // W frag source: cb*24576 + kb*1536 + half*768 + g*256 + quad*64 + wn*32 + ch*16 + lr
    const u16x8* pw = wst + (size_t)cb * 24576 + quad * 64 + wn * 32 + lr;

    f32x4 aR[4][2], aZ[4][2], aNi[4][2], aNh[4][2];
    #pragma unroll
    for (int rh = 0; rh < 4; ++rh)
        #pragma unroll
        for (int ch = 0; ch < 2; ++ch) {
            aR[rh][ch]  = (f32x4){0.f, 0.f, 0.f, 0.f};
            aZ[rh][ch]  = (f32x4){0.f, 0.f, 0.f, 0.f};
            aNi[rh][ch] = (f32x4){0.f, 0.f, 0.f, 0.f};
            aNh[rh][ch] = (f32x4){0.f, 0.f, 0.f, 0.f};
        }

    bf16x8 ax[4], wx[3][2];   // X set (A from xt, W = Wih r/z/n)
    bf16x8 ah[4], wh[3][2];   // H set (A from ht, W = Whh r/z/n)

    auto loadA = [&](const u16x8* base, int kb, bf16x8 (&av)[4]) {
        const u16x8* pa = base + (size_t)kb * 4 * B;
        #pragma unroll
        for (int rh = 0; rh < 4; ++rh)
            av[rh] = *(const bf16x8*)&pa[rh * 16];
    };
    auto loadW = [&](int kb, int half, bf16x8 (&wv)[3][2]) {
        const u16x8* pq = pw + (size_t)kb * 1536 + half * 768;
        #pragma unroll
        for (int g = 0; g < 3; ++g) {
            wv[g][0] = *(const bf16x8*)&pq[g * 256];
            wv[g][1] = *(const bf16x8*)&pq[g * 256 + 16];
        }
    };
    auto mfma_half = [&](bf16x8 (&av)[4], bf16x8 (&wv)[3][2], f32x4 (&accN)[4][2]) {
        __builtin_amdgcn_s_setprio(1);
        #pragma unroll
        for (int rh = 0; rh < 4; ++rh)
            #pragma unroll
            for (int ch = 0; ch < 2; ++ch) {
                aR[rh][ch]   = __builtin_amdgcn_mfma_f32_16x16x32_bf16(av[rh], wv[0][ch], aR[rh][ch], 0, 0, 0);
                aZ[rh][ch]   = __builtin_amdgcn_mfma_f32_16x16x32_bf16(av[rh], wv[1][ch], aZ[rh][ch], 0, 0, 0);
                accN[rh][ch] = __builtin_amdgcn_mfma_f32_16x16x32_bf16(av[rh], wv[2][ch], accN[rh][ch], 0, 0, 0);
            }
        __builtin_amdgcn_s_setprio(0);
    };

    // prologue: both sets of kb=0
    loadA(pax, 0, ax); loadW(0, 0, wx);
    loadA(pah, 0, ah); loadW(0, 1, wh);

    for (int kb = 0; kb < 16; ++kb) {
        // MFMA on X(kb); H(kb) loads (+X(kb+1) below) stay in flight
        mfma_half(ax, wx, aNi);
        if (kb < 15) { loadA(pax, kb + 1, ax); loadW(kb + 1, 0, wx); }
        mfma_half(ah, wh, aNh);
        if (kb < 15) { loadA(pah, kb + 1, ah); loadW(kb + 1, 1, wh); }
    }

    // epilogue: C/D layout col=lane&15, row=quad*4+reg
    #pragma unroll
    for (int ch = 0; ch < 2; ++ch) {
        int col = cb * 64 + wn * 32 + ch * 16 + lr;
        float br  = bih[col] + bhh[col];
        float bz  = bih[512 + col] + bhh[512 + col];
        float bin = bih[1024 + col];
        float bhn = bhh[1024 + col];
        #pragma unroll
        for (int rh = 0; rh < 4; ++rh)
            #pragma unroll
            for (int reg = 0; reg < 4; ++reg) {
                int row = r0 + wm * 64 + rh * 16 + quad * 4 + reg;
                float rg = sigm(aR[rh][ch][reg] + br);
                float zg = sigm(aZ[rh][ch][reg] + bz);
                float ng = tanh_fast(aNi[rh][ch][reg] + bin + rg * (aNh[rh][ch][reg] + bhn));
                float ht_ = mh[row] * h[(size_t)row * 512 + col];
                out[(size_t)row * 512 + col] = (1.f - zg) * ng + zg * ht_;
            }
    }
}

// ---------------------------------------------------------------------------
// 4) exp-map in place
// ---------------------------------------------------------------------------
__global__ void expmap_kernel(float* __restrict__ out, int D) {
    int wave = threadIdx.x >> 6;
    int lane = threadIdx.x & 63;
    int row = blockIdx.x * 4 + wave;
    float4* p = (float4*)(out + (size_t)row * D);
    float4 v0 = p[lane], v1 = p[lane + 64];
    float s = v0.x * v0.x + v0.y * v0.y + v0.z * v0.z + v0.w * v0.w
            + v1.x * v1.x + v1.y * v1.y + v1.z * v1.z + v1.w * v1.w;
    #pragma unroll
    for (int off = 32; off; off >>= 1) s += __shfl_xor(s, off);
    float norm = fmaxf(sqrtf(s), 1e-15f);
    float a = 0.1f * norm;
    float m = tanhf(a) / a;
    v0.x *= m; v0.y *= m; v0.z *= m; v0.w *= m;
    v1.x *= m; v1.y *= m; v1.z *= m; v1.w *= m;
    p[lane] = v0;
    p[lane + 64] = v1;
}

extern "C" void kernel_launch(void* const* d_in, const int* in_sizes, int n_in,
                              void* d_out, int out_size, void* d_ws, size_t ws_size,
                              hipStream_t stream) {
    const float* x   = (const float*)d_in[0];
    const float* h   = (const float*)d_in[1];
    const float* Wih = (const float*)d_in[2];
    const float* Whh = (const float*)d_in[3];
    const float* bih = (const float*)d_in[4];
    const float* bhh = (const float*)d_in[5];
    float* out = (float*)d_out;

    int H = in_sizes[4] / 3;          // 512
    int I = in_sizes[2] / (3 * H);    // 512
    int B = in_sizes[0] / I;          // 32768

    u16x8* xt  = (u16x8*)d_ws;
    u16x8* ht  = xt + (size_t)64 * B;
    u16x8* wst = ht + (size_t)64 * B;
    float* mh  = (float*)(wst + 196608);

    prep_kernel<<<dim3(B / 32, 2), 256, 0, stream>>>(x, h, xt, ht, mh, B);
    wcvt_kernel<<<768, 256, 0, stream>>>(Wih, Whh, wst);
    gru_gemm_kernel<<<(B / 128) * 8, 256, 0, stream>>>(xt, ht, wst, h, mh, bih, bhh, out, B);
    expmap_kernel<<<B / 4, 256, 0, stream>>>(out, H);
}